// Round 1
// baseline (1584.918 us; speedup 1.0000x reference)
//
#include <hip/hip_runtime.h>
#include <stdint.h>

#define T_TOKENS 8192
#define DDIM 1024
#define FDIM 3584
#define NEXP 8

#define BM 128
#define BN1 64
#define BN2 128
#define BK 64
#define LDK 72   // BK + 8 pad (keeps 16B alignment for b128 reads, breaks pow2 bank stride)
#define MAXRT (T_TOKENS / BM)

typedef _Float16 f16x8 __attribute__((ext_vector_type(8)));
typedef _Float16 f16x4 __attribute__((ext_vector_type(4)));
typedef _Float16 f16x2 __attribute__((ext_vector_type(2)));
typedef float f32x4 __attribute__((ext_vector_type(4)));

// ---------------- router: logits (fp32), softmax, top-2, expert lists ----------------
__global__ __launch_bounds__(256) void router_kernel(
    const float* __restrict__ x, const float* __restrict__ gw,
    float* __restrict__ logits_out, int* __restrict__ counts,
    int* __restrict__ tok_idx, float* __restrict__ tok_w) {
  int t = blockIdx.x * 4 + (threadIdx.x >> 6);  // one wave per token
  int lane = threadIdx.x & 63;
  const float* xr = x + (size_t)t * DDIM;
  float acc[NEXP];
#pragma unroll
  for (int e = 0; e < NEXP; e++) acc[e] = 0.f;
  for (int c = 0; c < DDIM / 64; c++) {
    float xv = xr[c * 64 + lane];
#pragma unroll
    for (int e = 0; e < NEXP; e++) acc[e] += xv * gw[e * DDIM + c * 64 + lane];
  }
#pragma unroll
  for (int e = 0; e < NEXP; e++) {
    for (int off = 32; off > 0; off >>= 1) acc[e] += __shfl_xor(acc[e], off, 64);
  }
  if (lane == 0) {
    float m = acc[0];
    for (int e = 1; e < NEXP; e++) m = fmaxf(m, acc[e]);
    float p[NEXP];
    for (int e = 0; e < NEXP; e++) p[e] = expf(acc[e] - m);
    int e1 = 0;
    for (int e = 1; e < NEXP; e++) if (p[e] > p[e1]) e1 = e;  // strict > : lowest idx on tie (jax rule)
    int e2 = (e1 == 0) ? 1 : 0;
    for (int e = 0; e < NEXP; e++) { if (e == e1) continue; if (p[e] > p[e2]) e2 = e; }
    float wsum = p[e1] + p[e2];
    float w1v = p[e1] / wsum, w2v = p[e2] / wsum;
    for (int e = 0; e < NEXP; e++) logits_out[(size_t)t * NEXP + e] = acc[e];
    int pos1 = atomicAdd(&counts[e1], 1);
    tok_idx[e1 * T_TOKENS + pos1] = t; tok_w[e1 * T_TOKENS + pos1] = w1v;
    int pos2 = atomicAdd(&counts[e2], 1);
    tok_idx[e2 * T_TOKENS + pos2] = t; tok_w[e2 * T_TOKENS + pos2] = w2v;
  }
}

__global__ void prefix_kernel(const int* __restrict__ counts, int* __restrict__ offsets) {
  if (threadIdx.x == 0) {
    int s = 0;
    for (int e = 0; e < NEXP; e++) { offsets[e] = s; s += counts[e]; }
    offsets[NEXP] = s;
  }
}

// ---------------- GEMM1: h = silu(x@w1) * (x@w3), gathered rows, per expert ----------------
// grid: (FDIM/BN1, MAXRT, NEXP), block 256. MFMA 16x16x32 f16, fragments A[m][k], B[n][k].
__global__ __launch_bounds__(256) void gemm1_kernel(
    const float* __restrict__ x, const float* __restrict__ w1,
    const float* __restrict__ w3, const int* __restrict__ counts,
    const int* __restrict__ offsets, const int* __restrict__ tok_idx,
    _Float16* __restrict__ h) {
  int e = blockIdx.z;
  int cnt = counts[e];
  int rt = blockIdx.y;
  if (rt * BM >= cnt) return;
  int ct = blockIdx.x;
  int off = offsets[e];

  __shared__ _Float16 lA[BM * LDK];
  __shared__ _Float16 lB1[BN1 * LDK];
  __shared__ _Float16 lB3[BN1 * LDK];

  int tid = threadIdx.x;
  int lane = tid & 63;
  int wave = tid >> 6;

  // A staging: 2 threads per row, 32 k each
  int arow = tid >> 1;
  int akoff = (tid & 1) * 32;
  int irow = rt * BM + arow;
  int clamped = irow < cnt ? irow : cnt - 1;
  int tA = tok_idx[e * T_TOKENS + clamped];
  const float* xrow = x + (size_t)tA * DDIM;

  // B staging (transpose k-major -> [n][k]): 2x2 micro-tiles
  int bn2 = (tid & 31) * 2;   // n pair base, 0..62
  int bk8 = tid >> 5;         // 0..7
  const float* w1b = w1 + (size_t)e * DDIM * FDIM + (size_t)ct * BN1;
  const float* w3b = w3 + (size_t)e * DDIM * FDIM + (size_t)ct * BN1;

  f32x4 acc1[2][4], acc3[2][4];
  f32x4 zero = {0.f, 0.f, 0.f, 0.f};
#pragma unroll
  for (int i = 0; i < 2; i++)
#pragma unroll
    for (int j = 0; j < 4; j++) { acc1[i][j] = zero; acc3[i][j] = zero; }

  int wm = wave * 32;       // wave covers rows [wm, wm+32), all 64 cols
  int l15 = lane & 15;
  int q8 = (lane >> 4) * 8;

  for (int kt = 0; kt < DDIM / BK; kt++) {
    {
      const float* src = xrow + kt * BK + akoff;
      _Float16* dst = &lA[arow * LDK + akoff];
#pragma unroll
      for (int q = 0; q < 8; q++) {
        float4 v = ((const float4*)src)[q];
        f16x4 o = {(_Float16)v.x, (_Float16)v.y, (_Float16)v.z, (_Float16)v.w};
        *(f16x4*)(dst + q * 4) = o;
      }
    }
#pragma unroll
    for (int r = 0; r < 4; r++) {
      int kl = r * 16 + 2 * bk8;
      size_t g0 = (size_t)(kt * BK + kl) * FDIM + bn2;
      float2 a0 = *(const float2*)(w1b + g0);
      float2 a1 = *(const float2*)(w1b + g0 + FDIM);
      float2 c0 = *(const float2*)(w3b + g0);
      float2 c1 = *(const float2*)(w3b + g0 + FDIM);
      f16x2 p0 = {(_Float16)a0.x, (_Float16)a1.x};
      f16x2 p1 = {(_Float16)a0.y, (_Float16)a1.y};
      f16x2 p2 = {(_Float16)c0.x, (_Float16)c1.x};
      f16x2 p3 = {(_Float16)c0.y, (_Float16)c1.y};
      *(f16x2*)&lB1[bn2 * LDK + kl] = p0;
      *(f16x2*)&lB1[(bn2 + 1) * LDK + kl] = p1;
      *(f16x2*)&lB3[bn2 * LDK + kl] = p2;
      *(f16x2*)&lB3[(bn2 + 1) * LDK + kl] = p3;
    }
    __syncthreads();
#pragma unroll
    for (int kk = 0; kk < 2; kk++) {
      int ko = kk * 32 + q8;
      f16x8 af[2], b1f[4], b3f[4];
#pragma unroll
      for (int i = 0; i < 2; i++) af[i] = *(const f16x8*)&lA[(wm + i * 16 + l15) * LDK + ko];
#pragma unroll
      for (int j = 0; j < 4; j++) {
        b1f[j] = *(const f16x8*)&lB1[(j * 16 + l15) * LDK + ko];
        b3f[j] = *(const f16x8*)&lB3[(j * 16 + l15) * LDK + ko];
      }
#pragma unroll
      for (int i = 0; i < 2; i++)
#pragma unroll
        for (int j = 0; j < 4; j++) {
          acc1[i][j] = __builtin_amdgcn_mfma_f32_16x16x32_f16(af[i], b1f[j], acc1[i][j], 0, 0, 0);
          acc3[i][j] = __builtin_amdgcn_mfma_f32_16x16x32_f16(af[i], b3f[j], acc3[i][j], 0, 0, 0);
        }
    }
    __syncthreads();
  }
  // epilogue: C/D layout col=lane&15, row=(lane>>4)*4+reg (m89-verified mapping)
  int q4 = (lane >> 4) * 4;
#pragma unroll
  for (int i = 0; i < 2; i++) {
#pragma unroll
    for (int r = 0; r < 4; r++) {
      int row = rt * BM + wm + i * 16 + q4 + r;
      if (row >= cnt) continue;
      _Float16* hrow = h + (size_t)(off + row) * FDIM + (size_t)ct * BN1;
#pragma unroll
      for (int j = 0; j < 4; j++) {
        float a = acc1[i][j][r];
        float b = acc3[i][j][r];
        float hv = (a / (1.f + __expf(-a))) * b;
        hrow[j * 16 + l15] = (_Float16)hv;
      }
    }
  }
}

// ---------------- GEMM2: out[t] += w * (h @ w2[e]) ----------------
// grid: (DDIM/BN2, MAXRT, NEXP), block 256
__global__ __launch_bounds__(256) void gemm2_kernel(
    const _Float16* __restrict__ h, const float* __restrict__ w2,
    const int* __restrict__ counts, const int* __restrict__ offsets,
    const int* __restrict__ tok_idx, const float* __restrict__ tok_w,
    float* __restrict__ out) {
  int e = blockIdx.z;
  int cnt = counts[e];
  int rt = blockIdx.y;
  if (rt * BM >= cnt) return;
  int ct = blockIdx.x;
  int off = offsets[e];

  __shared__ _Float16 lA[BM * LDK];
  __shared__ _Float16 lB[BN2 * LDK];

  int tid = threadIdx.x;
  int lane = tid & 63;
  int wave = tid >> 6;

  int arow = tid >> 1;
  int akoff = (tid & 1) * 32;
  const _Float16* hrow = h + (size_t)(off + rt * BM + arow) * FDIM;

  int bn2v = (tid & 63) * 2;  // 0..126
  int bk4 = tid >> 6;         // 0..3
  const float* w2b = w2 + (size_t)e * FDIM * DDIM + (size_t)ct * BN2;

  f32x4 acc[2][8];
  f32x4 zero = {0.f, 0.f, 0.f, 0.f};
#pragma unroll
  for (int i = 0; i < 2; i++)
#pragma unroll
    for (int j = 0; j < 8; j++) acc[i][j] = zero;

  int wm = wave * 32;
  int l15 = lane & 15;
  int q8 = (lane >> 4) * 8;

  for (int kt = 0; kt < FDIM / BK; kt++) {
    {
      const uint4* src = (const uint4*)(hrow + kt * BK + akoff);
      uint4* dst = (uint4*)&lA[arow * LDK + akoff];
#pragma unroll
      for (int q = 0; q < 4; q++) dst[q] = src[q];
    }
#pragma unroll
    for (int r = 0; r < 8; r++) {
      int kl = r * 8 + 2 * bk4;
      size_t g0 = (size_t)(kt * BK + kl) * DDIM + bn2v;
      float2 a0 = *(const float2*)(w2b + g0);
      float2 a1 = *(const float2*)(w2b + g0 + DDIM);
      f16x2 p0 = {(_Float16)a0.x, (_Float16)a1.x};
      f16x2 p1 = {(_Float16)a0.y, (_Float16)a1.y};
      *(f16x2*)&lB[bn2v * LDK + kl] = p0;
      *(f16x2*)&lB[(bn2v + 1) * LDK + kl] = p1;
    }
    __syncthreads();
#pragma unroll
    for (int kk = 0; kk < 2; kk++) {
      int ko = kk * 32 + q8;
      f16x8 af[2], bf[8];
#pragma unroll
      for (int i = 0; i < 2; i++) af[i] = *(const f16x8*)&lA[(wm + i * 16 + l15) * LDK + ko];
#pragma unroll
      for (int j = 0; j < 8; j++) bf[j] = *(const f16x8*)&lB[(j * 16 + l15) * LDK + ko];
#pragma unroll
      for (int i = 0; i < 2; i++)
#pragma unroll
        for (int j = 0; j < 8; j++)
          acc[i][j] = __builtin_amdgcn_mfma_f32_16x16x32_f16(af[i], bf[j], acc[i][j], 0, 0, 0);
    }
    __syncthreads();
  }
  int q4 = (lane >> 4) * 4;
#pragma unroll
  for (int i = 0; i < 2; i++) {
#pragma unroll
    for (int r = 0; r < 4; r++) {
      int row = rt * BM + wm + i * 16 + q4 + r;
      if (row >= cnt) continue;
      int t = tok_idx[e * T_TOKENS + row];
      float wgt = tok_w[e * T_TOKENS + row];
      float* orow = out + (size_t)t * DDIM + (size_t)ct * BN2;
#pragma unroll
      for (int j = 0; j < 8; j++)
        atomicAdd(&orow[j * 16 + l15], acc[i][j][r] * wgt);
    }
  }
}

// Workspace layout (bytes):
//   [0,32)        counts[8]
//   [64,100)      offsets[9]
//   [256, +256KB) tok_idx[E*T]
//   then tok_w[E*T] (256KB), then h: (16384+128) x 3584 f16 = 118.4 MB
//   total ~113.5 MB required.
extern "C" void kernel_launch(void* const* d_in, const int* in_sizes, int n_in,
                              void* d_out, int out_size, void* d_ws, size_t ws_size,
                              hipStream_t stream) {
  const float* x  = (const float*)d_in[0];
  const float* gw = (const float*)d_in[1];
  const float* w1 = (const float*)d_in[2];
  const float* w3 = (const float*)d_in[3];
  const float* w2 = (const float*)d_in[4];
  float* out = (float*)d_out;
  float* logits = out + (size_t)T_TOKENS * DDIM;

  char* ws = (char*)d_ws;
  int* counts  = (int*)ws;
  int* offsets = (int*)(ws + 64);
  int* tok_idx = (int*)(ws + 256);
  float* tok_w = (float*)(ws + 256 + (size_t)NEXP * T_TOKENS * 4);
  _Float16* h  = (_Float16*)(ws + 256 + (size_t)2 * NEXP * T_TOKENS * 4 + 256);

  hipMemsetAsync(counts, 0, 256, stream);
  hipMemsetAsync(out, 0, (size_t)T_TOKENS * DDIM * 4, stream);

  router_kernel<<<T_TOKENS / 4, 256, 0, stream>>>(x, gw, logits, counts, tok_idx, tok_w);
  prefix_kernel<<<1, 64, 0, stream>>>(counts, offsets);
  gemm1_kernel<<<dim3(FDIM / BN1, MAXRT, NEXP), 256, 0, stream>>>(x, w1, w3, counts, offsets, tok_idx, h);
  gemm2_kernel<<<dim3(DDIM / BN2, MAXRT, NEXP), 256, 0, stream>>>(h, w2, counts, offsets, tok_idx, tok_w, out);
}

// Round 2
// 1148.723 us; speedup vs baseline: 1.3797x; 1.3797x over previous
//
#include <hip/hip_runtime.h>
#include <stdint.h>

#define T_TOKENS 8192
#define DDIM 1024
#define FDIM 3584
#define NEXP 8

#define BM 128
#define BK 64
#define MAXRT (T_TOKENS / BM)
#define H_ROWS (2 * T_TOKENS + BM)  // padded so gemm2 tail rows stay in-bounds

typedef _Float16 f16x8 __attribute__((ext_vector_type(8)));
typedef _Float16 f16x4 __attribute__((ext_vector_type(4)));
typedef float f32x4 __attribute__((ext_vector_type(4)));

__device__ __forceinline__ void gload16(const void* g, void* l) {
  __builtin_amdgcn_global_load_lds(
      (const __attribute__((address_space(1))) void*)g,
      (__attribute__((address_space(3))) void*)l, 16, 0, 0);
}

// ---------------- router: logits (fp32), softmax, top-2, expert lists ----------------
__global__ __launch_bounds__(256) void router_kernel(
    const float* __restrict__ x, const float* __restrict__ gw,
    float* __restrict__ logits_out, int* __restrict__ counts,
    int* __restrict__ tok_idx, float* __restrict__ tok_w) {
  int t = blockIdx.x * 4 + (threadIdx.x >> 6);  // one wave per token
  int lane = threadIdx.x & 63;
  const float* xr = x + (size_t)t * DDIM;
  float acc[NEXP];
#pragma unroll
  for (int e = 0; e < NEXP; e++) acc[e] = 0.f;
  for (int c = 0; c < DDIM / 64; c++) {
    float xv = xr[c * 64 + lane];
#pragma unroll
    for (int e = 0; e < NEXP; e++) acc[e] += xv * gw[e * DDIM + c * 64 + lane];
  }
#pragma unroll
  for (int e = 0; e < NEXP; e++) {
    for (int off = 32; off > 0; off >>= 1) acc[e] += __shfl_xor(acc[e], off, 64);
  }
  if (lane == 0) {
    float m = acc[0];
    for (int e = 1; e < NEXP; e++) m = fmaxf(m, acc[e]);
    float p[NEXP];
    for (int e = 0; e < NEXP; e++) p[e] = expf(acc[e] - m);
    int e1 = 0;
    for (int e = 1; e < NEXP; e++) if (p[e] > p[e1]) e1 = e;  // strict > : lowest idx on tie
    int e2 = (e1 == 0) ? 1 : 0;
    for (int e = 0; e < NEXP; e++) { if (e == e1) continue; if (p[e] > p[e2]) e2 = e; }
    float wsum = p[e1] + p[e2];
    float w1v = p[e1] / wsum, w2v = p[e2] / wsum;
    for (int e = 0; e < NEXP; e++) logits_out[(size_t)t * NEXP + e] = acc[e];
    int pos1 = atomicAdd(&counts[e1], 1);
    tok_idx[e1 * T_TOKENS + pos1] = t; tok_w[e1 * T_TOKENS + pos1] = w1v;
    int pos2 = atomicAdd(&counts[e2], 1);
    tok_idx[e2 * T_TOKENS + pos2] = t; tok_w[e2 * T_TOKENS + pos2] = w2v;
  }
}

__global__ void prefix_kernel(const int* __restrict__ counts, int* __restrict__ offsets) {
  if (threadIdx.x == 0) {
    int s = 0;
    for (int e = 0; e < NEXP; e++) { offsets[e] = s; s += counts[e]; }
    offsets[NEXP] = s;
  }
}

// ---------------- pre-pass: x fp32 -> f16 ----------------
__global__ __launch_bounds__(256) void convert_x_kernel(const float* __restrict__ x,
                                                        _Float16* __restrict__ xh) {
  int i = blockIdx.x * 256 + threadIdx.x;  // one f16x8 per thread
  const float4* s = (const float4*)x + (size_t)i * 2;
  float4 a = s[0], b = s[1];
  f16x8 o = {(_Float16)a.x, (_Float16)a.y, (_Float16)a.z, (_Float16)a.w,
             (_Float16)b.x, (_Float16)b.y, (_Float16)b.z, (_Float16)b.w};
  *((f16x8*)xh + i) = o;
}

// ---------------- pre-pass: transpose+convert  in[e][R][C] fp32 -> out[e][C][R] f16 ----------------
// grid (C/64, R/64, NEXP), block 256
__global__ __launch_bounds__(256) void transpose_f16_kernel(
    const float* __restrict__ in, _Float16* __restrict__ out, int R, int C) {
  __shared__ _Float16 lt[64][72];
  size_t esz = (size_t)R * C;
  in += blockIdx.z * esz;
  out += blockIdx.z * esz;
  int r0 = blockIdx.y * 64, c0 = blockIdx.x * 64;
  int t = threadIdx.x;
  int r = t >> 2, cs = (t & 3) * 16;
  const float* src = in + (size_t)(r0 + r) * C + c0 + cs;
#pragma unroll
  for (int q = 0; q < 4; q++) {
    float4 v = ((const float4*)src)[q];
    lt[cs + q * 4 + 0][r] = (_Float16)v.x;
    lt[cs + q * 4 + 1][r] = (_Float16)v.y;
    lt[cs + q * 4 + 2][r] = (_Float16)v.z;
    lt[cs + q * 4 + 3][r] = (_Float16)v.w;
  }
  __syncthreads();
  int cl = t >> 2, rs = (t & 3) * 16;
  _Float16* dst = out + (size_t)(c0 + cl) * R + r0 + rs;
#pragma unroll
  for (int q = 0; q < 2; q++)
    *(f16x8*)(dst + q * 8) = *(const f16x8*)&lt[cl][rs + q * 8];
}

// ---------------- GEMM1: h = silu(x@w1) * (x@w3), gathered rows ----------------
// A: xh gathered [128][64], B: w1t/w3t [e][F][D] f16, tiles [64][64]. All staged via
// global_load_lds w/ XOR-chunk swizzle (chunk = 8 halfwords = 16B; phys slot p holds
// logical chunk p^(row&7)). grid (FDIM/64, MAXRT, NEXP), block 256.
__global__ __launch_bounds__(256) void gemm1_kernel(
    const _Float16* __restrict__ xh, const _Float16* __restrict__ w1t,
    const _Float16* __restrict__ w3t, const int* __restrict__ counts,
    const int* __restrict__ offsets, const int* __restrict__ tok_idx,
    _Float16* __restrict__ h) {
  int e = blockIdx.z;
  int cnt = counts[e];
  int rt = blockIdx.y;
  if (rt * BM >= cnt) return;
  int ct = blockIdx.x;
  int off = offsets[e];

  __shared__ _Float16 lA[BM * 64];
  __shared__ _Float16 lB1[64 * 64];
  __shared__ _Float16 lB3[64 * 64];

  int tid = threadIdx.x, lane = tid & 63, w = tid >> 6;
  int p = lane & 7;       // physical chunk slot
  int rsub = lane >> 3;   // row within 8-row instr group
  int c = p ^ rsub;       // logical chunk to fetch

  // A staging: 4 instrs/wave, 8 rows each (gathered token rows)
  const _Float16* aG[4];
  _Float16* aL[4];
#pragma unroll
  for (int g = 0; g < 4; g++) {
    int r = w * 32 + g * 8 + rsub;
    int ir = rt * BM + r;
    if (ir >= cnt) ir = cnt - 1;
    int tok = tok_idx[e * T_TOKENS + ir];
    aG[g] = xh + (size_t)tok * DDIM + c * 8;
    aL[g] = lA + (w * 32 + g * 8) * 64;
  }
  // B staging: 2 instrs/wave each matrix
  const _Float16 *b1G[2], *b3G[2];
  _Float16 *b1L[2], *b3L[2];
#pragma unroll
  for (int g = 0; g < 2; g++) {
    int n = w * 16 + g * 8 + rsub;
    size_t row = (size_t)e * FDIM + (size_t)ct * 64 + n;
    b1G[g] = w1t + row * DDIM + c * 8;
    b3G[g] = w3t + row * DDIM + c * 8;
    b1L[g] = lB1 + (w * 16 + g * 8) * 64;
    b3L[g] = lB3 + (w * 16 + g * 8) * 64;
  }

  f32x4 acc1[2][4], acc3[2][4];
  f32x4 zero = {0.f, 0.f, 0.f, 0.f};
#pragma unroll
  for (int i = 0; i < 2; i++)
#pragma unroll
    for (int j = 0; j < 4; j++) { acc1[i][j] = zero; acc3[i][j] = zero; }

  int wm = w * 32;
  int l15 = lane & 15;
  int qv = lane >> 4;
  int x7 = l15 & 7;

  for (int kt = 0; kt < DDIM / BK; kt++) {
#pragma unroll
    for (int g = 0; g < 4; g++) { gload16(aG[g], aL[g]); aG[g] += 64; }
#pragma unroll
    for (int g = 0; g < 2; g++) {
      gload16(b1G[g], b1L[g]); b1G[g] += 64;
      gload16(b3G[g], b3L[g]); b3G[g] += 64;
    }
    __syncthreads();
#pragma unroll
    for (int kk = 0; kk < 2; kk++) {
      int pc = (kk * 4 + qv) ^ x7;  // physical chunk for logical ko
      f16x8 af[2], b1f[4], b3f[4];
#pragma unroll
      for (int i = 0; i < 2; i++)
        af[i] = *(const f16x8*)&lA[(wm + i * 16 + l15) * 64 + pc * 8];
#pragma unroll
      for (int j = 0; j < 4; j++) {
        b1f[j] = *(const f16x8*)&lB1[(j * 16 + l15) * 64 + pc * 8];
        b3f[j] = *(const f16x8*)&lB3[(j * 16 + l15) * 64 + pc * 8];
      }
#pragma unroll
      for (int i = 0; i < 2; i++)
#pragma unroll
        for (int j = 0; j < 4; j++) {
          acc1[i][j] = __builtin_amdgcn_mfma_f32_16x16x32_f16(af[i], b1f[j], acc1[i][j], 0, 0, 0);
          acc3[i][j] = __builtin_amdgcn_mfma_f32_16x16x32_f16(af[i], b3f[j], acc3[i][j], 0, 0, 0);
        }
    }
    __syncthreads();
  }
  int q4 = qv * 4;
#pragma unroll
  for (int i = 0; i < 2; i++) {
#pragma unroll
    for (int r = 0; r < 4; r++) {
      int row = rt * BM + wm + i * 16 + q4 + r;
      if (row >= cnt) continue;
      _Float16* hrow = h + (size_t)(off + row) * FDIM + (size_t)ct * 64;
#pragma unroll
      for (int j = 0; j < 4; j++) {
        float a = acc1[i][j][r];
        float b = acc3[i][j][r];
        float hv = (a / (1.f + __expf(-a))) * b;
        hrow[j * 16 + l15] = (_Float16)hv;
      }
    }
  }
}

// ---------------- GEMM2: out[t] += w * (h @ w2[e]) ----------------
// A: h rows (contiguous) [128][64], B: w2t [e][D][F] f16 tile [128][64].
// grid (DDIM/128, MAXRT, NEXP), block 256.
__global__ __launch_bounds__(256) void gemm2_kernel(
    const _Float16* __restrict__ h, const _Float16* __restrict__ w2t,
    const int* __restrict__ counts, const int* __restrict__ offsets,
    const int* __restrict__ tok_idx, const float* __restrict__ tok_w,
    float* __restrict__ out) {
  int e = blockIdx.z;
  int cnt = counts[e];
  int rt = blockIdx.y;
  if (rt * BM >= cnt) return;
  int ct = blockIdx.x;
  int off = offsets[e];

  __shared__ _Float16 lA[BM * 64];
  __shared__ _Float16 lB[128 * 64];

  int tid = threadIdx.x, lane = tid & 63, w = tid >> 6;
  int p = lane & 7;
  int rsub = lane >> 3;
  int c = p ^ rsub;

  const _Float16 *aG[4], *bG[4];
  _Float16 *aL[4], *bL[4];
#pragma unroll
  for (int g = 0; g < 4; g++) {
    int r = w * 32 + g * 8 + rsub;
    aG[g] = h + (size_t)(off + rt * BM + r) * FDIM + c * 8;
    aL[g] = lA + (w * 32 + g * 8) * 64;
    size_t row = (size_t)e * DDIM + (size_t)ct * 128 + r;
    bG[g] = w2t + row * FDIM + c * 8;
    bL[g] = lB + (w * 32 + g * 8) * 64;
  }

  f32x4 acc[2][8];
  f32x4 zero = {0.f, 0.f, 0.f, 0.f};
#pragma unroll
  for (int i = 0; i < 2; i++)
#pragma unroll
    for (int j = 0; j < 8; j++) acc[i][j] = zero;

  int wm = w * 32;
  int l15 = lane & 15;
  int qv = lane >> 4;
  int x7 = l15 & 7;

  for (int kt = 0; kt < FDIM / BK; kt++) {
#pragma unroll
    for (int g = 0; g < 4; g++) {
      gload16(aG[g], aL[g]); aG[g] += 64;
      gload16(bG[g], bL[g]); bG[g] += 64;
    }
    __syncthreads();
#pragma unroll
    for (int kk = 0; kk < 2; kk++) {
      int pc = (kk * 4 + qv) ^ x7;
      f16x8 af[2], bf[8];
#pragma unroll
      for (int i = 0; i < 2; i++)
        af[i] = *(const f16x8*)&lA[(wm + i * 16 + l15) * 64 + pc * 8];
#pragma unroll
      for (int j = 0; j < 8; j++)
        bf[j] = *(const f16x8*)&lB[(j * 16 + l15) * 64 + pc * 8];
#pragma unroll
      for (int i = 0; i < 2; i++)
#pragma unroll
        for (int j = 0; j < 8; j++)
          acc[i][j] = __builtin_amdgcn_mfma_f32_16x16x32_f16(af[i], bf[j], acc[i][j], 0, 0, 0);
    }
    __syncthreads();
  }
  int q4 = qv * 4;
#pragma unroll
  for (int i = 0; i < 2; i++) {
#pragma unroll
    for (int r = 0; r < 4; r++) {
      int row = rt * BM + wm + i * 16 + q4 + r;
      if (row >= cnt) continue;
      int t = tok_idx[e * T_TOKENS + row];
      float wgt = tok_w[e * T_TOKENS + row];
      float* orow = out + (size_t)t * DDIM + (size_t)ct * 128;
#pragma unroll
      for (int j = 0; j < 8; j++)
        atomicAdd(&orow[j * 16 + l15], acc[i][j][r] * wgt);
    }
  }
}

// Workspace layout (MiB offsets; total required ~= 298 MiB):
//   0: counts/offsets/tok_idx/tok_w (<1 MiB)
//   1: xh  (16 MiB)   17: w1t (56 MiB)   73: w3t (56 MiB)   129: w2t (56 MiB)
//   185: h  ((16384+128) x 3584 f16 = ~113 MiB)
extern "C" void kernel_launch(void* const* d_in, const int* in_sizes, int n_in,
                              void* d_out, int out_size, void* d_ws, size_t ws_size,
                              hipStream_t stream) {
  const float* x  = (const float*)d_in[0];
  const float* gw = (const float*)d_in[1];
  const float* w1 = (const float*)d_in[2];
  const float* w3 = (const float*)d_in[3];
  const float* w2 = (const float*)d_in[4];
  float* out = (float*)d_out;
  float* logits = out + (size_t)T_TOKENS * DDIM;

  char* ws = (char*)d_ws;
  const size_t MB = 1024 * 1024;
  int* counts  = (int*)ws;
  int* offsets = (int*)(ws + 64);
  int* tok_idx = (int*)(ws + 256);
  float* tok_w = (float*)(ws + 256 + (size_t)NEXP * T_TOKENS * 4);
  _Float16* xh  = (_Float16*)(ws + 1 * MB);
  _Float16* w1t = (_Float16*)(ws + 17 * MB);
  _Float16* w3t = (_Float16*)(ws + 73 * MB);
  _Float16* w2t = (_Float16*)(ws + 129 * MB);
  _Float16* h   = (_Float16*)(ws + 185 * MB);

  hipMemsetAsync(counts, 0, 256, stream);
  hipMemsetAsync(out, 0, (size_t)T_TOKENS * DDIM * 4, stream);

  convert_x_kernel<<<T_TOKENS * DDIM / 8 / 256, 256, 0, stream>>>(x, xh);
  transpose_f16_kernel<<<dim3(FDIM / 64, DDIM / 64, NEXP), 256, 0, stream>>>(w1, w1t, DDIM, FDIM);
  transpose_f16_kernel<<<dim3(FDIM / 64, DDIM / 64, NEXP), 256, 0, stream>>>(w3, w3t, DDIM, FDIM);
  transpose_f16_kernel<<<dim3(DDIM / 64, FDIM / 64, NEXP), 256, 0, stream>>>(w2, w2t, FDIM, DDIM);

  router_kernel<<<T_TOKENS / 4, 256, 0, stream>>>(x, gw, logits, counts, tok_idx, tok_w);
  prefix_kernel<<<1, 64, 0, stream>>>(counts, offsets);

  gemm1_kernel<<<dim3(FDIM / 64, MAXRT, NEXP), 256, 0, stream>>>(xh, w1t, w3t, counts, offsets, tok_idx, h);
  gemm2_kernel<<<dim3(DDIM / 128, MAXRT, NEXP), 256, 0, stream>>>(h, w2t, counts, offsets, tok_idx, tok_w, out);
}

// Round 3
// 1139.731 us; speedup vs baseline: 1.3906x; 1.0079x over previous
//
#include <hip/hip_runtime.h>
#include <stdint.h>

#define T_TOKENS 8192
#define DDIM 1024
#define FDIM 3584
#define NEXP 8

#define BM 128
#define BK 64
#define MAXTT 136  // max row-tiles: 16384/128 + 8 rounding

typedef _Float16 f16x8 __attribute__((ext_vector_type(8)));
typedef float f32x4 __attribute__((ext_vector_type(4)));

__device__ __forceinline__ void gload16(const void* g, void* l) {
  __builtin_amdgcn_global_load_lds(
      (const __attribute__((address_space(1))) void*)g,
      (__attribute__((address_space(3))) void*)l, 16, 0, 0);
}

// ---------------- router: logits, softmax, top-2, expert lists; also emits xh=f16(x) ----
__global__ __launch_bounds__(256) void router_kernel(
    const float* __restrict__ x, const float* __restrict__ gw,
    float* __restrict__ logits_out, int* __restrict__ counts,
    int* __restrict__ tok_idx, float* __restrict__ tok_w,
    int2* __restrict__ tok_ref, _Float16* __restrict__ xh) {
  int t = blockIdx.x * 4 + (threadIdx.x >> 6);  // one wave per token
  int lane = threadIdx.x & 63;
  const float* xr = x + (size_t)t * DDIM;
  float acc[NEXP];
#pragma unroll
  for (int e = 0; e < NEXP; e++) acc[e] = 0.f;
  for (int c = 0; c < DDIM / 64; c++) {
    float xv = xr[c * 64 + lane];
    xh[(size_t)t * DDIM + c * 64 + lane] = (_Float16)xv;
#pragma unroll
    for (int e = 0; e < NEXP; e++) acc[e] += xv * gw[e * DDIM + c * 64 + lane];
  }
#pragma unroll
  for (int e = 0; e < NEXP; e++) {
    for (int off = 32; off > 0; off >>= 1) acc[e] += __shfl_xor(acc[e], off, 64);
  }
  if (lane == 0) {
    float m = acc[0];
    for (int e = 1; e < NEXP; e++) m = fmaxf(m, acc[e]);
    float p[NEXP];
    for (int e = 0; e < NEXP; e++) p[e] = expf(acc[e] - m);
    int e1 = 0;
    for (int e = 1; e < NEXP; e++) if (p[e] > p[e1]) e1 = e;  // strict > : lowest idx on tie
    int e2 = (e1 == 0) ? 1 : 0;
    for (int e = 0; e < NEXP; e++) { if (e == e1) continue; if (p[e] > p[e2]) e2 = e; }
    float wsum = p[e1] + p[e2];
    float w1v = p[e1] / wsum, w2v = p[e2] / wsum;
    for (int e = 0; e < NEXP; e++) logits_out[(size_t)t * NEXP + e] = acc[e];
    int pos1 = atomicAdd(&counts[e1], 1);
    tok_idx[e1 * T_TOKENS + pos1] = t; tok_w[e1 * T_TOKENS + pos1] = w1v;
    int pos2 = atomicAdd(&counts[e2], 1);
    tok_idx[e2 * T_TOKENS + pos2] = t; tok_w[e2 * T_TOKENS + pos2] = w2v;
    tok_ref[t] = make_int2((e1 << 13) | pos1, (e2 << 13) | pos2);
  }
}

// ---------------- prefix + compact tile schedule ----------------
__global__ void prefix_kernel(const int* __restrict__ counts, int* __restrict__ offsets,
                              int* __restrict__ sched) {
  if (threadIdx.x == 0) {
    int s = 0, nt = 0;
    for (int e = 0; e < NEXP; e++) {
      offsets[e] = s;
      int c = counts[e];
      int ntile = (c + BM - 1) / BM;
      for (int i = 0; i < ntile; i++) sched[nt++] = (e << 16) | i;
      s += c;
    }
    offsets[NEXP] = s;
    for (; nt < MAXTT; nt++) sched[nt] = -1;
  }
}

// ---------------- transpose+convert: in[e][R][C] fp32 -> out[e][C][R] f16 ----------------
// Phase 1: scalar-scatter store lt[c][r] (row uniform per instr -> 32 banks, no conflicts).
// Phase 2: b128 row reads (8 distinct bank-quads x 8 lanes = full-rate), coalesced f16x8 out.
__global__ __launch_bounds__(256) void transpose_f16_kernel(
    const float* __restrict__ in, _Float16* __restrict__ out, int R, int C) {
  __shared__ _Float16 lt[64][72];
  size_t esz = (size_t)R * C;
  in += (size_t)blockIdx.z * esz;
  out += (size_t)blockIdx.z * esz;
  int r0 = blockIdx.y * 64, c0 = blockIdx.x * 64;
  int t = threadIdx.x;
  int r = t & 63, q = t >> 6;
  const float* src = in + (size_t)(r0 + r) * C + c0 + q * 16;
  float4 v0 = ((const float4*)src)[0];
  float4 v1 = ((const float4*)src)[1];
  float4 v2 = ((const float4*)src)[2];
  float4 v3 = ((const float4*)src)[3];
  _Float16 f[16] = {
      (_Float16)v0.x, (_Float16)v0.y, (_Float16)v0.z, (_Float16)v0.w,
      (_Float16)v1.x, (_Float16)v1.y, (_Float16)v1.z, (_Float16)v1.w,
      (_Float16)v2.x, (_Float16)v2.y, (_Float16)v2.z, (_Float16)v2.w,
      (_Float16)v3.x, (_Float16)v3.y, (_Float16)v3.z, (_Float16)v3.w};
#pragma unroll
  for (int j = 0; j < 16; j++) lt[q * 16 + j][r] = f[j];
  __syncthreads();
  _Float16* dst = out + (size_t)(c0 + r) * R + r0 + q * 16;
  *(f16x8*)dst       = *(const f16x8*)&lt[r][q * 16];
  *(f16x8*)(dst + 8) = *(const f16x8*)&lt[r][q * 16 + 8];
}

// ---------------- GEMM1: h = silu(x@w1) * (x@w3), gathered rows ----------------
// grid (FDIM/64, MAXTT), block 256. XOR-chunk swizzled global_load_lds staging.
__global__ __launch_bounds__(256) void gemm1_kernel(
    const _Float16* __restrict__ xh, const _Float16* __restrict__ w1t,
    const _Float16* __restrict__ w3t, const int* __restrict__ counts,
    const int* __restrict__ offsets, const int* __restrict__ tok_idx,
    const int* __restrict__ sched, _Float16* __restrict__ h) {
  int sc = sched[blockIdx.y];
  if (sc < 0) return;
  int e = sc >> 16, rt = sc & 0xFFFF;
  int cnt = counts[e];
  int ct = blockIdx.x;
  int off = offsets[e];

  __shared__ _Float16 lA[BM * 64];
  __shared__ _Float16 lB1[64 * 64];
  __shared__ _Float16 lB3[64 * 64];

  int tid = threadIdx.x, lane = tid & 63, w = tid >> 6;
  int p = lane & 7;       // physical chunk slot
  int rsub = lane >> 3;   // row within 8-row instr group
  int c = p ^ rsub;       // logical chunk to fetch

  const _Float16* aG[4];
  _Float16* aL[4];
#pragma unroll
  for (int g = 0; g < 4; g++) {
    int r = w * 32 + g * 8 + rsub;
    int ir = rt * BM + r;
    if (ir >= cnt) ir = cnt - 1;
    int tok = tok_idx[e * T_TOKENS + ir];
    aG[g] = xh + (size_t)tok * DDIM + c * 8;
    aL[g] = lA + (w * 32 + g * 8) * 64;
  }
  const _Float16 *b1G[2], *b3G[2];
  _Float16 *b1L[2], *b3L[2];
#pragma unroll
  for (int g = 0; g < 2; g++) {
    int n = w * 16 + g * 8 + rsub;
    size_t row = (size_t)e * FDIM + (size_t)ct * 64 + n;
    b1G[g] = w1t + row * DDIM + c * 8;
    b3G[g] = w3t + row * DDIM + c * 8;
    b1L[g] = lB1 + (w * 16 + g * 8) * 64;
    b3L[g] = lB3 + (w * 16 + g * 8) * 64;
  }

  f32x4 acc1[2][4], acc3[2][4];
  f32x4 zero = {0.f, 0.f, 0.f, 0.f};
#pragma unroll
  for (int i = 0; i < 2; i++)
#pragma unroll
    for (int j = 0; j < 4; j++) { acc1[i][j] = zero; acc3[i][j] = zero; }

  int wm = w * 32;
  int l15 = lane & 15;
  int qv = lane >> 4;
  int x7 = l15 & 7;

  for (int kt = 0; kt < DDIM / BK; kt++) {
#pragma unroll
    for (int g = 0; g < 4; g++) { gload16(aG[g], aL[g]); aG[g] += 64; }
#pragma unroll
    for (int g = 0; g < 2; g++) {
      gload16(b1G[g], b1L[g]); b1G[g] += 64;
      gload16(b3G[g], b3L[g]); b3G[g] += 64;
    }
    __syncthreads();
#pragma unroll
    for (int kk = 0; kk < 2; kk++) {
      int pc = (kk * 4 + qv) ^ x7;
      f16x8 af[2], b1f[4], b3f[4];
#pragma unroll
      for (int i = 0; i < 2; i++)
        af[i] = *(const f16x8*)&lA[(wm + i * 16 + l15) * 64 + pc * 8];
#pragma unroll
      for (int j = 0; j < 4; j++) {
        b1f[j] = *(const f16x8*)&lB1[(j * 16 + l15) * 64 + pc * 8];
        b3f[j] = *(const f16x8*)&lB3[(j * 16 + l15) * 64 + pc * 8];
      }
#pragma unroll
      for (int i = 0; i < 2; i++)
#pragma unroll
        for (int j = 0; j < 4; j++) {
          acc1[i][j] = __builtin_amdgcn_mfma_f32_16x16x32_f16(af[i], b1f[j], acc1[i][j], 0, 0, 0);
          acc3[i][j] = __builtin_amdgcn_mfma_f32_16x16x32_f16(af[i], b3f[j], acc3[i][j], 0, 0, 0);
        }
    }
    __syncthreads();
  }
  int q4 = qv * 4;
#pragma unroll
  for (int i = 0; i < 2; i++) {
#pragma unroll
    for (int r = 0; r < 4; r++) {
      int row = rt * BM + wm + i * 16 + q4 + r;
      if (row >= cnt) continue;
      _Float16* hrow = h + (size_t)(off + row) * FDIM + (size_t)ct * 64;
#pragma unroll
      for (int j = 0; j < 4; j++) {
        float a = acc1[i][j][r];
        float b = acc3[i][j][r];
        float hv = (a / (1.f + __expf(-a))) * b;
        hrow[j * 16 + l15] = (_Float16)hv;
      }
    }
  }
}

// ---------------- GEMM2: part[slot] = w * (h[slot] @ w2[e]) -- no atomics ----------------
// grid (DDIM/128, MAXTT), block 256.
__global__ __launch_bounds__(256) void gemm2_kernel(
    const _Float16* __restrict__ h, const _Float16* __restrict__ w2t,
    const int* __restrict__ counts, const int* __restrict__ offsets,
    const float* __restrict__ tok_w, const int* __restrict__ sched,
    _Float16* __restrict__ part) {
  int sc = sched[blockIdx.y];
  if (sc < 0) return;
  int e = sc >> 16, rt = sc & 0xFFFF;
  int cnt = counts[e];
  int ct = blockIdx.x;
  int off = offsets[e];

  __shared__ _Float16 lA[BM * 64];
  __shared__ _Float16 lB[128 * 64];

  int tid = threadIdx.x, lane = tid & 63, w = tid >> 6;
  int p = lane & 7;
  int rsub = lane >> 3;
  int c = p ^ rsub;

  const _Float16 *aG[4], *bG[4];
  _Float16 *aL[4], *bL[4];
#pragma unroll
  for (int g = 0; g < 4; g++) {
    int r = w * 32 + g * 8 + rsub;
    aG[g] = h + (size_t)(off + rt * BM + r) * FDIM + c * 8;
    aL[g] = lA + (w * 32 + g * 8) * 64;
    size_t row = (size_t)e * DDIM + (size_t)ct * 128 + r;
    bG[g] = w2t + row * FDIM + c * 8;
    bL[g] = lB + (w * 32 + g * 8) * 64;
  }

  f32x4 acc[2][8];
  f32x4 zero = {0.f, 0.f, 0.f, 0.f};
#pragma unroll
  for (int i = 0; i < 2; i++)
#pragma unroll
    for (int j = 0; j < 8; j++) acc[i][j] = zero;

  int wm = w * 32;
  int l15 = lane & 15;
  int qv = lane >> 4;
  int x7 = l15 & 7;

  for (int kt = 0; kt < FDIM / BK; kt++) {
#pragma unroll
    for (int g = 0; g < 4; g++) {
      gload16(aG[g], aL[g]); aG[g] += 64;
      gload16(bG[g], bL[g]); bG[g] += 64;
    }
    __syncthreads();
#pragma unroll
    for (int kk = 0; kk < 2; kk++) {
      int pc = (kk * 4 + qv) ^ x7;
      f16x8 af[2], bf[8];
#pragma unroll
      for (int i = 0; i < 2; i++)
        af[i] = *(const f16x8*)&lA[(wm + i * 16 + l15) * 64 + pc * 8];
#pragma unroll
      for (int j = 0; j < 8; j++)
        bf[j] = *(const f16x8*)&lB[(j * 16 + l15) * 64 + pc * 8];
#pragma unroll
      for (int i = 0; i < 2; i++)
#pragma unroll
        for (int j = 0; j < 8; j++)
          acc[i][j] = __builtin_amdgcn_mfma_f32_16x16x32_f16(af[i], bf[j], acc[i][j], 0, 0, 0);
    }
    __syncthreads();
  }
  int q4 = qv * 4;
#pragma unroll
  for (int i = 0; i < 2; i++) {
#pragma unroll
    for (int r = 0; r < 4; r++) {
      int row = rt * BM + wm + i * 16 + q4 + r;
      if (row >= cnt) continue;
      float wgt = tok_w[e * T_TOKENS + row];
      _Float16* prow = part + (size_t)(off + row) * DDIM + (size_t)ct * 128;
#pragma unroll
      for (int j = 0; j < 8; j++)
        prow[j * 16 + l15] = (_Float16)(acc[i][j][r] * wgt);
    }
  }
}

// ---------------- gather: out[t] = part[slotA(t)] + part[slotB(t)] ----------------
__global__ __launch_bounds__(256) void gather_kernel(
    const _Float16* __restrict__ part, const int2* __restrict__ tok_ref,
    const int* __restrict__ offsets, float* __restrict__ out) {
  int i = blockIdx.x * 256 + threadIdx.x;
  int t = i >> 7;            // 128 chunks of 8 per token
  int dc = (i & 127) * 8;
  int2 ref = tok_ref[t];
  int sa = offsets[ref.x >> 13] + (ref.x & 8191);
  int sb = offsets[ref.y >> 13] + (ref.y & 8191);
  f16x8 pa = *(const f16x8*)(part + (size_t)sa * DDIM + dc);
  f16x8 pb = *(const f16x8*)(part + (size_t)sb * DDIM + dc);
  float* dst = out + (size_t)t * DDIM + dc;
#pragma unroll
  for (int j = 0; j < 8; j++) dst[j] = (float)pa[j] + (float)pb[j];
}

// Workspace layout (MiB offsets; high-water ~= 338 MiB):
//   0: counts/offsets/sched/tok_idx/tok_w/tok_ref (<1 MiB)
//   1: xh 16 | 17: w1t 56 | 73: w3t 56 | 129: w2t 56 | 185: h 118.4 | 304: part 33.6
extern "C" void kernel_launch(void* const* d_in, const int* in_sizes, int n_in,
                              void* d_out, int out_size, void* d_ws, size_t ws_size,
                              hipStream_t stream) {
  const float* x  = (const float*)d_in[0];
  const float* gw = (const float*)d_in[1];
  const float* w1 = (const float*)d_in[2];
  const float* w3 = (const float*)d_in[3];
  const float* w2 = (const float*)d_in[4];
  float* out = (float*)d_out;
  float* logits = out + (size_t)T_TOKENS * DDIM;

  char* ws = (char*)d_ws;
  const size_t MB = 1024 * 1024;
  int* counts  = (int*)ws;
  int* offsets = (int*)(ws + 64);
  int* sched   = (int*)(ws + 128);               // 136 ints
  int* tok_idx = (int*)(ws + 1024);              // 256 KB
  float* tok_w = (float*)(ws + 1024 + 262144);   // 256 KB
  int2* tok_ref = (int2*)(ws + 1024 + 2 * 262144);  // 64 KB
  _Float16* xh  = (_Float16*)(ws + 1 * MB);
  _Float16* w1t = (_Float16*)(ws + 17 * MB);
  _Float16* w3t = (_Float16*)(ws + 73 * MB);
  _Float16* w2t = (_Float16*)(ws + 129 * MB);
  _Float16* h   = (_Float16*)(ws + 185 * MB);
  _Float16* part = (_Float16*)(ws + 304 * MB);

  hipMemsetAsync(counts, 0, 256, stream);

  router_kernel<<<T_TOKENS / 4, 256, 0, stream>>>(x, gw, logits, counts, tok_idx, tok_w, tok_ref, xh);
  prefix_kernel<<<1, 64, 0, stream>>>(counts, offsets, sched);

  transpose_f16_kernel<<<dim3(FDIM / 64, DDIM / 64, NEXP), 256, 0, stream>>>(w1, w1t, DDIM, FDIM);
  transpose_f16_kernel<<<dim3(FDIM / 64, DDIM / 64, NEXP), 256, 0, stream>>>(w3, w3t, DDIM, FDIM);
  transpose_f16_kernel<<<dim3(DDIM / 64, FDIM / 64, NEXP), 256, 0, stream>>>(w2, w2t, FDIM, DDIM);

  gemm1_kernel<<<dim3(FDIM / 64, MAXTT), 256, 0, stream>>>(xh, w1t, w3t, counts, offsets, tok_idx, sched, h);
  gemm2_kernel<<<dim3(DDIM / 128, MAXTT), 256, 0, stream>>>(h, w2t, counts, offsets, tok_w, sched, part);
  gather_kernel<<<T_TOKENS * DDIM / 8 / 256, 256, 0, stream>>>(part, tok_ref, offsets, out);
}